// Round 4
// baseline (635.441 us; speedup 1.0000x reference)
//
#include <hip/hip_runtime.h>

#define NUM_BASIS 67    // GRID_SIZE + K = 64 + 3
#define NTHREADS 256

// Interior knots: knots[i] = (i-35)/32 for i in [3,67]; clamped to -1 / +1
// outside. EXACT in float32, so comparisons reproduce the reference's
// indicator semantics bit-exactly.
__device__ __forceinline__ float kv(int i) {
    i = min(max(i, 3), 67);
    return (float)(i - 35) * 0.03125f;
}

// Sparse scatter: the output has already been zeroed by hipMemsetAsync (which
// runs as the rocclr fillBuffer kernel -- measured 6.26 TB/s on this exact
// buffer). Each row has at most 4 nonzero basis values, contiguous at columns
// [m-3, m]; each thread owns one row, so the 4-float write is race-free.
// Traffic: 8 MB coalesced x-read + 32 MB scattered write, vs. the previous
// kernel's 536 MB LDS-staged full-row stream that ran at only ~3.2 TB/s.
__global__ __launch_bounds__(NTHREADS) void SplineBasis_scatter(const float* __restrict__ x,
                                                                float* __restrict__ out,
                                                                int B) {
    const int row = blockIdx.x * NTHREADS + threadIdx.x;
    if (row >= B) return;

    const float xv = x[row];
    // Reference gives an all-zero row for x < -1, x >= 1, or NaN (indicator
    // never fires): nothing to write, memset already produced the zeros.
    if (!(xv >= -1.0f && xv < 1.0f)) return;

    // Containing interval: knots[m] <= x < knots[m+1], m in [3,66].
    int cell = (int)floorf((xv + 1.0f) * 32.0f);
    cell = min(max(cell, 0), 63);
    int m = cell + 3;
    // Fix-up against exact knot values (handles (x+1)*32 rounding at knot
    // boundaries so we match the reference's comparisons).
    while (m > 3 && xv < kv(m)) --m;
    while (m < 66 && xv >= kv(m + 1)) ++m;

    // de Boor triangle: after degree-3 loop, N[j] = B_{m-3+j,3}(x).
    // Identical values to the reference's bottom-up DP (the where(den!=0)
    // guards in the reference only zero out terms whose multiplying basis
    // entry is already zero).
    float N[4], left[4], right[4];
    N[0] = 1.0f;
#pragma unroll
    for (int d = 1; d <= 3; ++d) {
        left[d]  = xv - kv(m + 1 - d);
        right[d] = kv(m + d) - xv;
        float saved = 0.0f;
#pragma unroll
        for (int r = 0; r < d; ++r) {
            float temp = N[r] / (right[r + 1] + left[d - r]);
            N[r] = saved + right[r + 1] * temp;
            saved = left[d - r] * temp;
        }
        N[d] = saved;
    }

    // 4 scalar dword stores (base is only 4B-aligned; m-3 in [0, 63] keeps
    // all four inside this row).
    float* o = out + (size_t)row * NUM_BASIS + (m - 3);
    o[0] = N[0];
    o[1] = N[1];
    o[2] = N[2];
    o[3] = N[3];
}

extern "C" void kernel_launch(void* const* d_in, const int* in_sizes, int n_in,
                              void* d_out, int out_size, void* d_ws, size_t ws_size,
                              hipStream_t stream) {
    const float* x = (const float*)d_in[0];
    float* out = (float*)d_out;
    const int B = in_sizes[0];

    // Bulk zeros via the driver fill path (6.26 TB/s measured on this buffer).
    // hipMemsetAsync is stream-capture-safe (recorded as a graph memset node).
    hipMemsetAsync(out, 0, (size_t)B * NUM_BASIS * sizeof(float), stream);

    const int nblocks = (B + NTHREADS - 1) / NTHREADS;
    SplineBasis_scatter<<<nblocks, NTHREADS, 0, stream>>>(x, out, B);
}

// Round 6
// 524.964 us; speedup vs baseline: 1.2104x; 1.2104x over previous
//
#include <hip/hip_runtime.h>

#define ROWS_PER_BLOCK 128
#define NUM_BASIS 67                              // GRID_SIZE + K = 64 + 3
#define TILE_FLOATS (ROWS_PER_BLOCK * NUM_BASIS)  // 8576 floats = 34304 B
#define TILE_VEC4 (TILE_FLOATS / 4)               // 2144 (divisible: 8576 % 4 == 0)

// Interior knots: knots[i] = (i-35)/32 for i in [3,67]; clamped to -1 / +1 outside.
// These values are EXACT in float32, so comparisons reproduce the reference's
// indicator semantics bit-exactly.
__device__ __forceinline__ float kv(int i) {
    i = min(max(i, 3), 67);
    return (float)(i - 35) * 0.03125f;
}

// Measured-best structure (513.2 us total window). Under the calibrated cost
// model: kernel ~87 us = 544 MB at 6.26 TB/s (the write roofline demonstrated
// by the rocclr fill on this same buffer). Tested-and-rejected variants:
//   - 64-row tile + nontemporal stores + early x load: +14 us (NT loses L2
//     write-combining; occupancy was never the limiter)
//   - persistent 1024-block + lgkm-only barriers: +20 us
//   - hipMemsetAsync zeros + 4-float scatter: +122 us (partial-line RMW)
__global__ __launch_bounds__(256) void SplineBasis_kernel(const float* __restrict__ x,
                                                          float* __restrict__ out,
                                                          int B) {
    __shared__ __align__(16) float tile[TILE_FLOATS];
    const int tid = threadIdx.x;
    const int blockRow0 = blockIdx.x * ROWS_PER_BLOCK;

    // Phase 1: zero the LDS tile (the 63 zero columns per row).
    float4* t4 = (float4*)tile;
    for (int i = tid; i < TILE_VEC4; i += 256) t4[i] = make_float4(0.f, 0.f, 0.f, 0.f);
    __syncthreads();

    // Phase 2: threads 0..127 each compute one row's 4 nonzero basis values.
    if (tid < ROWS_PER_BLOCK) {
        const int row = blockRow0 + tid;
        if (row < B) {
            const float xv = x[row];
            // Reference gives an all-zero row for x < -1, x >= 1, or NaN
            // (indicator never fires). Input is uniform in [-1, 1).
            if (xv >= -1.0f && xv < 1.0f) {
                // Containing interval: knots[m] <= x < knots[m+1], m in [3,66].
                int cell = (int)floorf((xv + 1.0f) * 32.0f);
                cell = min(max(cell, 0), 63);
                int m = cell + 3;
                // Fix-up against exact knot values (handles (x+1)*32 rounding
                // at knot boundaries so we match the reference's comparisons).
                while (m > 3 && xv < kv(m)) --m;
                while (m < 66 && xv >= kv(m + 1)) ++m;

                // de Boor triangle: after degree-3 loop, N[j] = B_{m-3+j,3}(x).
                // Identical values to the reference's bottom-up DP (the
                // where(den!=0) guards in the reference only zero out terms
                // whose multiplying basis entry is already zero).
                float N[4], left[4], right[4];
                N[0] = 1.0f;
#pragma unroll
                for (int d = 1; d <= 3; ++d) {
                    left[d]  = xv - kv(m + 1 - d);
                    right[d] = kv(m + d) - xv;
                    float saved = 0.0f;
#pragma unroll
                    for (int r = 0; r < d; ++r) {
                        float temp = N[r] / (right[r + 1] + left[d - r]);
                        N[r] = saved + right[r + 1] * temp;
                        saved = left[d - r] * temp;
                    }
                    N[d] = saved;
                }

                const int c0 = tid * NUM_BASIS + (m - 3);  // m-3 in [0, 63]
                tile[c0 + 0] = N[0];
                tile[c0 + 1] = N[1];
                tile[c0 + 2] = N[2];
                tile[c0 + 3] = N[3];
            }
        }
    }
    __syncthreads();

    // Phase 3: stream the tile to global, fully coalesced float4 stores.
    // Tile base byte offset = blockIdx * 34304, which is 16B-aligned.
    const int rows = min(ROWS_PER_BLOCK, B - blockRow0);
    if (rows == ROWS_PER_BLOCK) {
        float4* o4 = (float4*)(out + (size_t)blockRow0 * NUM_BASIS);
        for (int i = tid; i < TILE_VEC4; i += 256) o4[i] = t4[i];
    } else if (rows > 0) {
        // Generic tail (not hit for B = 2,000,000: 2e6 % 128 == 0).
        const int n = rows * NUM_BASIS;
        float* o = out + (size_t)blockRow0 * NUM_BASIS;
        for (int i = tid; i < n; i += 256) o[i] = tile[i];
    }
}

extern "C" void kernel_launch(void* const* d_in, const int* in_sizes, int n_in,
                              void* d_out, int out_size, void* d_ws, size_t ws_size,
                              hipStream_t stream) {
    const float* x = (const float*)d_in[0];
    float* out = (float*)d_out;
    const int B = in_sizes[0];
    const int nblocks = (B + ROWS_PER_BLOCK - 1) / ROWS_PER_BLOCK;
    SplineBasis_kernel<<<nblocks, 256, 0, stream>>>(x, out, B);
}